// Round 1
// baseline (1101.542 us; speedup 1.0000x reference)
//
#include <hip/hip_runtime.h>

#define HWPX 9216   // 96*96
#define NCH  128

typedef float  f32x4  __attribute__((ext_vector_type(4)));
typedef __bf16 bf16x8 __attribute__((ext_vector_type(8)));

// ---------------------------------------------------------------------------
// prep: wt_j = w_j^T (c,o) fp32 for coalesced conv1x1 reads;
//       wck  = wc rearranged to (tap, o, c) bf16 for MFMA A-fragments.
// ---------------------------------------------------------------------------
__global__ __launch_bounds__(256) void prep_kernel(
    const float* __restrict__ w1, const float* __restrict__ w2,
    const float* __restrict__ w3, const float* __restrict__ wc,
    float* __restrict__ wt, __bf16* __restrict__ wck) {
  int tid = blockIdx.x * 256 + threadIdx.x;
  int nt  = gridDim.x * 256;
  for (int idx = tid; idx < 3 * 16384; idx += nt) {
    int j = idx >> 14;
    int rem = idx & 16383;
    int o = rem >> 7, c = rem & 127;
    const float* w = (j == 0) ? w1 : (j == 1 ? w2 : w3);
    wt[j * 16384 + c * 128 + o] = w[o * 128 + c];
  }
  for (int idx = tid; idx < 147456; idx += nt) {   // wc is (O=128, C=128, 3, 3)
    int k = idx % 9;
    int rest = idx / 9;            // o*128 + c
    int c = rest & 127, o = rest >> 7;
    wck[(k * 128 + o) * 128 + c] = (__bf16)wc[idx];
  }
}

// ---------------------------------------------------------------------------
// conv1x1 x3 + bias + PReLU.  in: (C, HW) fp32.
// Writes Q,K as (seq, d) bf16; V as (d, seq) bf16 (its native layout).
// Block: 256 threads, 32 pixels.  o = tid&127, pixel half = tid>>7.
// ---------------------------------------------------------------------------
__global__ __launch_bounds__(256) void conv1x1_qkv(
    const float* __restrict__ in, const float* __restrict__ wt,
    const float* __restrict__ b1, const float* __restrict__ b2,
    const float* __restrict__ b3, const float* __restrict__ a1,
    const float* __restrict__ a2, const float* __restrict__ a3,
    __bf16* __restrict__ Q, __bf16* __restrict__ K, __bf16* __restrict__ Vt) {
  __shared__ float xs[128][32];
  const int tid = threadIdx.x;
  const int p0  = blockIdx.x * 32;
#pragma unroll
  for (int i = 0; i < 4; ++i) {
    int id = tid + i * 256;          // 1024 float4 chunks
    int row = id >> 3, c4 = id & 7;
    *(float4*)&xs[row][c4 * 4] =
        *(const float4*)&in[row * HWPX + p0 + c4 * 4];
  }
  __syncthreads();
  const int o = tid & 127, g = tid >> 7;
  float acc1[16], acc2[16], acc3[16];
#pragma unroll
  for (int j = 0; j < 16; ++j) acc1[j] = acc2[j] = acc3[j] = 0.f;
  const float* wt1 = wt;
  const float* wt2 = wt + 16384;
  const float* wt3 = wt + 32768;
  for (int c = 0; c < 128; ++c) {
    float v1 = wt1[c * 128 + o];
    float v2 = wt2[c * 128 + o];
    float v3 = wt3[c * 128 + o];
#pragma unroll
    for (int j4 = 0; j4 < 4; ++j4) {
      f32x4 xv = *(const f32x4*)&xs[c][g * 16 + j4 * 4];
#pragma unroll
      for (int e = 0; e < 4; ++e) {
        acc1[j4 * 4 + e] += v1 * xv[e];
        acc2[j4 * 4 + e] += v2 * xv[e];
        acc3[j4 * 4 + e] += v3 * xv[e];
      }
    }
  }
  const float bb1 = b1[o], bb2 = b2[o], bb3 = b3[o];
  const float s1 = a1[0], s2 = a2[0], s3 = a3[0];
#pragma unroll
  for (int j = 0; j < 16; ++j) {
    int p = p0 + g * 16 + j;
    float v1 = acc1[j] + bb1; v1 = (v1 >= 0.f) ? v1 : s1 * v1;
    float v2 = acc2[j] + bb2; v2 = (v2 >= 0.f) ? v2 : s2 * v2;
    float v3 = acc3[j] + bb3; v3 = (v3 >= 0.f) ? v3 : s3 * v3;
    Q[p * 128 + o]   = (__bf16)v1;
    K[p * 128 + o]   = (__bf16)v2;
    Vt[o * HWPX + p] = (__bf16)v3;
  }
}

// ---------------------------------------------------------------------------
// Flash attention.  Q,K: (seq,d) bf16.  Vt: (d,seq) bf16.  att out: (seq,d) f32.
// Block = 256 thr (4 waves), 64 queries (16/wave).  Key tiles of 64.
// LDS: K tile [64][128] bf16 (16KB, XOR-swizzled) + V tile [128][64] bf16
// (16KB, XOR-swizzled) + per-wave P [16][64] bf16 (4x2KB, XOR-swizzled).
// ---------------------------------------------------------------------------
__global__ __launch_bounds__(256) void flash_attn(
    const __bf16* __restrict__ Q, const __bf16* __restrict__ Kb,
    const __bf16* __restrict__ Vt, float* __restrict__ att) {
  __shared__ __align__(16) unsigned char smem[40960];
  const int tid  = threadIdx.x;
  const int lane = tid & 63;
  const int w    = tid >> 6;
  const int l16  = lane & 15;
  const int hi   = lane >> 4;
  const int qb   = blockIdx.x * 64;

  // Q fragments held in registers for the whole kernel
  bf16x8 qf[4];
  const int qrow = qb + w * 16 + l16;
#pragma unroll
  for (int dc = 0; dc < 4; ++dc)
    qf[dc] = *(const bf16x8*)&Q[qrow * 128 + dc * 32 + hi * 8];

  f32x4 oacc[8];
#pragma unroll
  for (int dc = 0; dc < 8; ++dc) oacc[dc] = (f32x4){0.f, 0.f, 0.f, 0.f};
  float m[4], l[4];
#pragma unroll
  for (int r = 0; r < 4; ++r) { m[r] = -INFINITY; l[r] = 0.f; }

  const unsigned pbase = 32768 + w * 2048;

  for (int kt = 0; kt < 144; ++kt) {
    __syncthreads();
    // stage K tile: 64 rows x 256B, swizzled
#pragma unroll
    for (int i = 0; i < 4; ++i) {
      int id = tid + i * 256;
      int row = id >> 4, ch = id & 15;
      int4 v = *(const int4*)&Kb[(kt * 64 + row) * 128 + ch * 8];
      *(int4*)&smem[row * 256 + ((ch * 16) ^ ((row & 7) << 4))] = v;
    }
    // stage V tile: 128 rows x 128B, swizzled
#pragma unroll
    for (int i = 0; i < 4; ++i) {
      int id = tid + i * 256;
      int d = id >> 3, ch = id & 7;
      int4 v = *(const int4*)&Vt[d * HWPX + kt * 64 + ch * 8];
      *(int4*)&smem[16384 + d * 128 + ((ch * 16) ^ ((d & 7) << 4))] = v;
    }
    __syncthreads();

    // S = Q K^T   (16 queries x 64 keys per wave)
    f32x4 s[4];
#pragma unroll
    for (int g = 0; g < 4; ++g) {
      s[g] = (f32x4){0.f, 0.f, 0.f, 0.f};
      int row = g * 16 + l16;
#pragma unroll
      for (int dc = 0; dc < 4; ++dc) {
        bf16x8 kf = *(const bf16x8*)&smem[row * 256 +
                        ((dc * 64 + hi * 16) ^ ((row & 7) << 4))];
        s[g] = __builtin_amdgcn_mfma_f32_16x16x32_bf16(qf[dc], kf, s[g], 0, 0, 0);
      }
    }

    // online softmax (rows live on 16-lane groups; reduce via shfl_xor 1/2/4/8)
    float mx[4];
#pragma unroll
    for (int r = 0; r < 4; ++r) {
      mx[r] = fmaxf(fmaxf(s[0][r], s[1][r]), fmaxf(s[2][r], s[3][r]));
      mx[r] = fmaxf(mx[r], __shfl_xor(mx[r], 1));
      mx[r] = fmaxf(mx[r], __shfl_xor(mx[r], 2));
      mx[r] = fmaxf(mx[r], __shfl_xor(mx[r], 4));
      mx[r] = fmaxf(mx[r], __shfl_xor(mx[r], 8));
    }
    float alpha[4], rs[4];
#pragma unroll
    for (int r = 0; r < 4; ++r) {
      float mn = fmaxf(m[r], mx[r]);
      alpha[r] = __expf(m[r] - mn);
      m[r] = mn;
      rs[r] = 0.f;
    }
#pragma unroll
    for (int g = 0; g < 4; ++g)
#pragma unroll
      for (int r = 0; r < 4; ++r) {
        float p = __expf(s[g][r] - m[r]);
        s[g][r] = p;
        rs[r] += p;
      }
#pragma unroll
    for (int r = 0; r < 4; ++r) {
      rs[r] += __shfl_xor(rs[r], 1);
      rs[r] += __shfl_xor(rs[r], 2);
      rs[r] += __shfl_xor(rs[r], 4);
      rs[r] += __shfl_xor(rs[r], 8);
      l[r] = l[r] * alpha[r] + rs[r];
    }
#pragma unroll
    for (int dc = 0; dc < 8; ++dc)
#pragma unroll
      for (int r = 0; r < 4; ++r) oacc[dc][r] *= alpha[r];

    // P -> LDS (bf16, swizzled), then PV
#pragma unroll
    for (int g = 0; g < 4; ++g)
#pragma unroll
      for (int r = 0; r < 4; ++r) {
        int row = hi * 4 + r;
        *(__bf16*)&smem[pbase + row * 128 +
                        ((g * 32 + l16 * 2) ^ ((row & 7) << 4))] =
            (__bf16)s[g][r];
      }
    bf16x8 pa[2];
#pragma unroll
    for (int kc = 0; kc < 2; ++kc)
      pa[kc] = *(const bf16x8*)&smem[pbase + l16 * 128 +
                   ((kc * 64 + hi * 16) ^ ((l16 & 7) << 4))];
#pragma unroll
    for (int dc = 0; dc < 8; ++dc) {
#pragma unroll
      for (int kc = 0; kc < 2; ++kc) {
        int row = dc * 16 + l16;
        bf16x8 vf = *(const bf16x8*)&smem[16384 + row * 128 +
                        ((kc * 64 + hi * 16) ^ ((row & 7) << 4))];
        oacc[dc] = __builtin_amdgcn_mfma_f32_16x16x32_bf16(pa[kc], vf, oacc[dc], 0, 0, 0);
      }
    }
  }

  // epilogue: att[(q), d] = O / l
#pragma unroll
  for (int dc = 0; dc < 8; ++dc)
#pragma unroll
    for (int r = 0; r < 4; ++r) {
      int q = qb + w * 16 + hi * 4 + r;
      att[q * 128 + dc * 16 + l16] = oacc[dc][r] / l[r];
    }
}

// ---------------------------------------------------------------------------
// conv3x3 (SAME, zero pad) + bias + exact GELU, optional residual add.
// att in: (seq, d) fp32.  out: (C, HW) fp32.
// 9 shifted MFMA GEMMs over a zero-padded LDS halo (3 rows x 50 px, bf16).
// Block: 256 thr, tile = one y row x 48 px x all 128 o.  Grid: 96*2.
// ---------------------------------------------------------------------------
__global__ __launch_bounds__(256) void conv3x3_gelu(
    const float* __restrict__ att, const __bf16* __restrict__ wck,
    const float* __restrict__ bc, const float* __restrict__ resid,
    float* __restrict__ out) {
  __shared__ __align__(16) unsigned char smem[38400];  // 150 px * 256B
  const int tid = threadIdx.x;
  const int y   = blockIdx.x >> 1;
  const int x0  = (blockIdx.x & 1) * 48;
  const int lane = tid & 63, w = tid >> 6;
  const int l16 = lane & 15, hi = lane >> 4;

  for (int id = tid; id < 2400; id += 256) {     // 150 px x 16 chunks of 16B
    int px = id >> 4, ch = id & 15;
    int hy = px / 50, hx = px - hy * 50;
    int gy = y + hy - 1, gx = x0 + hx - 1;
    bf16x8 v;
    if (gy >= 0 && gy < 96 && gx >= 0 && gx < 96) {
      const float* src = &att[(gy * 96 + gx) * 128 + ch * 8];
      f32x4 aa = *(const f32x4*)src;
      f32x4 bb = *(const f32x4*)(src + 4);
#pragma unroll
      for (int e = 0; e < 4; ++e) { v[e] = (__bf16)aa[e]; v[4 + e] = (__bf16)bb[e]; }
    } else {
#pragma unroll
      for (int e = 0; e < 8; ++e) v[e] = (__bf16)0.f;
    }
    *(bf16x8*)&smem[px * 256 + ((ch * 16) ^ ((px & 7) << 4))] = v;
  }
  __syncthreads();

  f32x4 acc[2][3];
#pragma unroll
  for (int ot = 0; ot < 2; ++ot) {
    int obase = w * 32 + ot * 16 + hi * 4;
#pragma unroll
    for (int pt = 0; pt < 3; ++pt)
#pragma unroll
      for (int r = 0; r < 4; ++r) acc[ot][pt][r] = bc[obase + r];
  }

  for (int tap = 0; tap < 9; ++tap) {
    int dy = tap / 3, dx = tap - dy * 3;
#pragma unroll
    for (int cc = 0; cc < 4; ++cc) {
      bf16x8 af[2];
#pragma unroll
      for (int ot = 0; ot < 2; ++ot)
        af[ot] = *(const bf16x8*)&wck[(tap * 128 + w * 32 + ot * 16 + l16) * 128 +
                                      cc * 32 + hi * 8];
#pragma unroll
      for (int pt = 0; pt < 3; ++pt) {
        int px = dy * 50 + pt * 16 + l16 + dx;
        bf16x8 bf = *(const bf16x8*)&smem[px * 256 +
                        ((cc * 64 + hi * 16) ^ ((px & 7) << 4))];
#pragma unroll
        for (int ot = 0; ot < 2; ++ot)
          acc[ot][pt] = __builtin_amdgcn_mfma_f32_16x16x32_bf16(af[ot], bf, acc[ot][pt], 0, 0, 0);
      }
    }
  }

#pragma unroll
  for (int ot = 0; ot < 2; ++ot)
#pragma unroll
    for (int pt = 0; pt < 3; ++pt)
#pragma unroll
      for (int r = 0; r < 4; ++r) {
        int o  = w * 32 + ot * 16 + hi * 4 + r;
        int px = y * 96 + x0 + pt * 16 + l16;
        float v = acc[ot][pt][r];
        float ge = 0.5f * v * (1.f + erff(v * 0.70710678118654752f));
        if (resid) ge += resid[o * HWPX + px];
        out[o * HWPX + px] = ge;
      }
}

// ---------------------------------------------------------------------------
extern "C" void kernel_launch(void* const* d_in, const int* in_sizes, int n_in,
                              void* d_out, int out_size, void* d_ws, size_t ws_size,
                              hipStream_t stream) {
  const float* x  = (const float*)d_in[0];
  const float* w1 = (const float*)d_in[1];
  const float* b1 = (const float*)d_in[2];
  const float* a1 = (const float*)d_in[3];
  const float* w2 = (const float*)d_in[4];
  const float* b2 = (const float*)d_in[5];
  const float* a2 = (const float*)d_in[6];
  const float* w3 = (const float*)d_in[7];
  const float* b3 = (const float*)d_in[8];
  const float* a3 = (const float*)d_in[9];
  const float* wc = (const float*)d_in[10];
  const float* bc = (const float*)d_in[11];
  float* out = (float*)d_out;

  char* ws = (char*)d_ws;
  float*  res_a = (float*)(ws + 0);          // 4718592 B
  float*  res_b = (float*)(ws + 4718592);    // 4718592 B
  float*  att   = (float*)(ws + 9437184);    // 4718592 B
  __bf16* Qb    = (__bf16*)(ws + 14155776);  // 2359296 B
  __bf16* Kb    = (__bf16*)(ws + 16515072);  // 2359296 B
  __bf16* Vt    = (__bf16*)(ws + 18874368);  // 2359296 B
  float*  wt    = (float*)(ws + 21233664);   // 196608 B
  __bf16* wck   = (__bf16*)(ws + 21430272);  // 294912 B

  prep_kernel<<<576, 256, 0, stream>>>(w1, w2, w3, wc, wt, wck);

  const float* in = x;
  for (int u = 0; u < 3; ++u) {
    conv1x1_qkv<<<288, 256, 0, stream>>>(in, wt, b1, b2, b3, a1, a2, a3,
                                         Qb, Kb, Vt);
    flash_attn<<<144, 256, 0, stream>>>(Qb, Kb, Vt, att);
    float* o = (u == 0) ? res_a : ((u == 1) ? res_b : out);
    conv3x3_gelu<<<192, 256, 0, stream>>>(att, wck, bc,
                                          (u == 2) ? x : nullptr, o);
    in = o;
  }
}

// Round 2
// 658.243 us; speedup vs baseline: 1.6735x; 1.6735x over previous
//
#include <hip/hip_runtime.h>

#define HWPX 9216   // 96*96
#define NCH  128

typedef float  f32x4  __attribute__((ext_vector_type(4)));
typedef __bf16 bf16x8 __attribute__((ext_vector_type(8)));

// ---------------------------------------------------------------------------
// prep: wt_j = w_j^T (c,o) fp32 for coalesced conv1x1 reads;
//       wck  = wc rearranged to (tap, o, c) bf16 for MFMA A-fragments.
// ---------------------------------------------------------------------------
__global__ __launch_bounds__(256) void prep_kernel(
    const float* __restrict__ w1, const float* __restrict__ w2,
    const float* __restrict__ w3, const float* __restrict__ wc,
    float* __restrict__ wt, __bf16* __restrict__ wck) {
  int tid = blockIdx.x * 256 + threadIdx.x;
  int nt  = gridDim.x * 256;
  for (int idx = tid; idx < 3 * 16384; idx += nt) {
    int j = idx >> 14;
    int rem = idx & 16383;
    int o = rem >> 7, c = rem & 127;
    const float* w = (j == 0) ? w1 : (j == 1 ? w2 : w3);
    wt[j * 16384 + c * 128 + o] = w[o * 128 + c];
  }
  for (int idx = tid; idx < 147456; idx += nt) {   // wc is (O=128, C=128, 3, 3)
    int k = idx % 9;
    int rest = idx / 9;            // o*128 + c
    int c = rest & 127, o = rest >> 7;
    wck[(k * 128 + o) * 128 + c] = (__bf16)wc[idx];
  }
}

// ---------------------------------------------------------------------------
// conv1x1 x3 + bias + PReLU.  in: (C, HW) fp32.
// Writes Q,K as (seq, d) bf16; V as (d, seq) bf16 (its native layout).
// ---------------------------------------------------------------------------
__global__ __launch_bounds__(256) void conv1x1_qkv(
    const float* __restrict__ in, const float* __restrict__ wt,
    const float* __restrict__ b1, const float* __restrict__ b2,
    const float* __restrict__ b3, const float* __restrict__ a1,
    const float* __restrict__ a2, const float* __restrict__ a3,
    __bf16* __restrict__ Q, __bf16* __restrict__ K, __bf16* __restrict__ Vt) {
  __shared__ float xs[128][32];
  const int tid = threadIdx.x;
  const int p0  = blockIdx.x * 32;
#pragma unroll
  for (int i = 0; i < 4; ++i) {
    int id = tid + i * 256;          // 1024 float4 chunks
    int row = id >> 3, c4 = id & 7;
    *(float4*)&xs[row][c4 * 4] =
        *(const float4*)&in[row * HWPX + p0 + c4 * 4];
  }
  __syncthreads();
  const int o = tid & 127, g = tid >> 7;
  float acc1[16], acc2[16], acc3[16];
#pragma unroll
  for (int j = 0; j < 16; ++j) acc1[j] = acc2[j] = acc3[j] = 0.f;
  const float* wt1 = wt;
  const float* wt2 = wt + 16384;
  const float* wt3 = wt + 32768;
  for (int c = 0; c < 128; ++c) {
    float v1 = wt1[c * 128 + o];
    float v2 = wt2[c * 128 + o];
    float v3 = wt3[c * 128 + o];
#pragma unroll
    for (int j4 = 0; j4 < 4; ++j4) {
      f32x4 xv = *(const f32x4*)&xs[c][g * 16 + j4 * 4];
#pragma unroll
      for (int e = 0; e < 4; ++e) {
        acc1[j4 * 4 + e] += v1 * xv[e];
        acc2[j4 * 4 + e] += v2 * xv[e];
        acc3[j4 * 4 + e] += v3 * xv[e];
      }
    }
  }
  const float bb1 = b1[o], bb2 = b2[o], bb3 = b3[o];
  const float s1 = a1[0], s2 = a2[0], s3 = a3[0];
#pragma unroll
  for (int j = 0; j < 16; ++j) {
    int p = p0 + g * 16 + j;
    float v1 = acc1[j] + bb1; v1 = (v1 >= 0.f) ? v1 : s1 * v1;
    float v2 = acc2[j] + bb2; v2 = (v2 >= 0.f) ? v2 : s2 * v2;
    float v3 = acc3[j] + bb3; v3 = (v3 >= 0.f) ? v3 : s3 * v3;
    Q[p * 128 + o]   = (__bf16)v1;
    K[p * 128 + o]   = (__bf16)v2;
    Vt[o * HWPX + p] = (__bf16)v3;
  }
}

// ---------------------------------------------------------------------------
// Flash attention with split-K.  Q,K: (seq,d) bf16.  Vt: (d,seq) bf16.
// Block = 256 thr (4 waves), 64 queries (16/wave).  Key tiles of 64.
// blockIdx.x = query block (144), blockIdx.y = key split.
// If mOut != nullptr: writes UNnormalized Opart + per-query m,l.
// Else: normalizes and writes att directly (single-split fallback).
// ---------------------------------------------------------------------------
__global__ __launch_bounds__(256) void flash_attn(
    const __bf16* __restrict__ Q, const __bf16* __restrict__ Kb,
    const __bf16* __restrict__ Vt, float* __restrict__ att,
    float* __restrict__ Opart, float* __restrict__ mOut,
    float* __restrict__ lOut, int tiles_per_split) {
  __shared__ __align__(16) unsigned char smem[40960];
  const int tid  = threadIdx.x;
  const int lane = tid & 63;
  const int w    = tid >> 6;
  const int l16  = lane & 15;
  const int hi   = lane >> 4;
  const int qb   = blockIdx.x * 64;
  const int kt0  = blockIdx.y * tiles_per_split;
  const int kt1  = kt0 + tiles_per_split;

  // Q fragments held in registers for the whole kernel
  bf16x8 qf[4];
  const int qrow = qb + w * 16 + l16;
#pragma unroll
  for (int dc = 0; dc < 4; ++dc)
    qf[dc] = *(const bf16x8*)&Q[qrow * 128 + dc * 32 + hi * 8];

  f32x4 oacc[8];
#pragma unroll
  for (int dc = 0; dc < 8; ++dc) oacc[dc] = (f32x4){0.f, 0.f, 0.f, 0.f};
  float m[4], l[4];
#pragma unroll
  for (int r = 0; r < 4; ++r) { m[r] = -INFINITY; l[r] = 0.f; }

  const unsigned pbase = 32768 + w * 2048;

  for (int kt = kt0; kt < kt1; ++kt) {
    __syncthreads();
    // stage K tile: 64 rows x 256B, swizzled
#pragma unroll
    for (int i = 0; i < 4; ++i) {
      int id = tid + i * 256;
      int row = id >> 4, ch = id & 15;
      int4 v = *(const int4*)&Kb[(kt * 64 + row) * 128 + ch * 8];
      *(int4*)&smem[row * 256 + ((ch * 16) ^ ((row & 7) << 4))] = v;
    }
    // stage V tile: 128 rows x 128B, swizzled
#pragma unroll
    for (int i = 0; i < 4; ++i) {
      int id = tid + i * 256;
      int d = id >> 3, ch = id & 7;
      int4 v = *(const int4*)&Vt[d * HWPX + kt * 64 + ch * 8];
      *(int4*)&smem[16384 + d * 128 + ((ch * 16) ^ ((d & 7) << 4))] = v;
    }
    __syncthreads();

    // S = Q K^T   (16 queries x 64 keys per wave)
    f32x4 s[4];
#pragma unroll
    for (int g = 0; g < 4; ++g) {
      s[g] = (f32x4){0.f, 0.f, 0.f, 0.f};
      int row = g * 16 + l16;
#pragma unroll
      for (int dc = 0; dc < 4; ++dc) {
        bf16x8 kf = *(const bf16x8*)&smem[row * 256 +
                        ((dc * 64 + hi * 16) ^ ((row & 7) << 4))];
        s[g] = __builtin_amdgcn_mfma_f32_16x16x32_bf16(qf[dc], kf, s[g], 0, 0, 0);
      }
    }

    // online softmax (rows live on 16-lane groups; reduce via shfl_xor 1/2/4/8)
    float mx[4];
#pragma unroll
    for (int r = 0; r < 4; ++r) {
      mx[r] = fmaxf(fmaxf(s[0][r], s[1][r]), fmaxf(s[2][r], s[3][r]));
      mx[r] = fmaxf(mx[r], __shfl_xor(mx[r], 1));
      mx[r] = fmaxf(mx[r], __shfl_xor(mx[r], 2));
      mx[r] = fmaxf(mx[r], __shfl_xor(mx[r], 4));
      mx[r] = fmaxf(mx[r], __shfl_xor(mx[r], 8));
    }
    float alpha[4], rs[4];
#pragma unroll
    for (int r = 0; r < 4; ++r) {
      float mn = fmaxf(m[r], mx[r]);
      alpha[r] = __expf(m[r] - mn);
      m[r] = mn;
      rs[r] = 0.f;
    }
#pragma unroll
    for (int g = 0; g < 4; ++g)
#pragma unroll
      for (int r = 0; r < 4; ++r) {
        float p = __expf(s[g][r] - m[r]);
        s[g][r] = p;
        rs[r] += p;
      }
#pragma unroll
    for (int r = 0; r < 4; ++r) {
      rs[r] += __shfl_xor(rs[r], 1);
      rs[r] += __shfl_xor(rs[r], 2);
      rs[r] += __shfl_xor(rs[r], 4);
      rs[r] += __shfl_xor(rs[r], 8);
      l[r] = l[r] * alpha[r] + rs[r];
    }
#pragma unroll
    for (int dc = 0; dc < 8; ++dc)
#pragma unroll
      for (int r = 0; r < 4; ++r) oacc[dc][r] *= alpha[r];

    // P -> LDS (bf16, swizzled), then PV
#pragma unroll
    for (int g = 0; g < 4; ++g)
#pragma unroll
      for (int r = 0; r < 4; ++r) {
        int row = hi * 4 + r;
        *(__bf16*)&smem[pbase + row * 128 +
                        ((g * 32 + l16 * 2) ^ ((row & 7) << 4))] =
            (__bf16)s[g][r];
      }
    bf16x8 pa[2];
#pragma unroll
    for (int kc = 0; kc < 2; ++kc)
      pa[kc] = *(const bf16x8*)&smem[pbase + l16 * 128 +
                   ((kc * 64 + hi * 16) ^ ((l16 & 7) << 4))];
#pragma unroll
    for (int dc = 0; dc < 8; ++dc) {
#pragma unroll
      for (int kc = 0; kc < 2; ++kc) {
        int row = dc * 16 + l16;
        bf16x8 vf = *(const bf16x8*)&smem[16384 + row * 128 +
                        ((kc * 64 + hi * 16) ^ ((row & 7) << 4))];
        oacc[dc] = __builtin_amdgcn_mfma_f32_16x16x32_bf16(pa[kc], vf, oacc[dc], 0, 0, 0);
      }
    }
  }

  if (mOut) {
    // split-K path: unnormalized partial O + (m,l) per query
    const int sbase = blockIdx.y * HWPX;
#pragma unroll
    for (int dc = 0; dc < 8; ++dc)
#pragma unroll
      for (int r = 0; r < 4; ++r) {
        int q = qb + w * 16 + hi * 4 + r;
        Opart[(size_t)(sbase + q) * 128 + dc * 16 + l16] = oacc[dc][r];
      }
    if (l16 == 0) {
#pragma unroll
      for (int r = 0; r < 4; ++r) {
        int q = qb + w * 16 + hi * 4 + r;
        mOut[sbase + q] = m[r];
        lOut[sbase + q] = l[r];
      }
    }
  } else {
#pragma unroll
    for (int dc = 0; dc < 8; ++dc)
#pragma unroll
      for (int r = 0; r < 4; ++r) {
        int q = qb + w * 16 + hi * 4 + r;
        att[q * 128 + dc * 16 + l16] = oacc[dc][r] / l[r];
      }
  }
}

// ---------------------------------------------------------------------------
// combine split-K partials: att = sum_i exp(m_i-M) O_i / sum_i exp(m_i-M) l_i
// one f32x4 per thread.  grid = 9216*32/256 = 1152.
// ---------------------------------------------------------------------------
__global__ __launch_bounds__(256) void flash_combine(
    const float* __restrict__ Opart, const float* __restrict__ mArr,
    const float* __restrict__ lArr, float* __restrict__ att, int ksplit) {
  int idx = blockIdx.x * 256 + threadIdx.x;   // q*32 + d4
  int q = idx >> 5, d4 = idx & 31;
  float M = -INFINITY;
  for (int i = 0; i < ksplit; ++i) M = fmaxf(M, mArr[i * HWPX + q]);
  float denom = 0.f;
  f32x4 acc = (f32x4){0.f, 0.f, 0.f, 0.f};
  for (int i = 0; i < ksplit; ++i) {
    float wi = __expf(mArr[i * HWPX + q] - M);
    denom += lArr[i * HWPX + q] * wi;
    f32x4 v = *(const f32x4*)&Opart[((size_t)i * HWPX + q) * 128 + d4 * 4];
#pragma unroll
    for (int e = 0; e < 4; ++e) acc[e] += wi * v[e];
  }
  float inv = 1.f / denom;
  f32x4 r;
#pragma unroll
  for (int e = 0; e < 4; ++e) r[e] = acc[e] * inv;
  *(f32x4*)&att[(size_t)q * 128 + d4 * 4] = r;
}

// ---------------------------------------------------------------------------
// conv3x3 (SAME, zero pad) + bias + exact GELU, optional residual add.
// ---------------------------------------------------------------------------
__global__ __launch_bounds__(256) void conv3x3_gelu(
    const float* __restrict__ att, const __bf16* __restrict__ wck,
    const float* __restrict__ bc, const float* __restrict__ resid,
    float* __restrict__ out) {
  __shared__ __align__(16) unsigned char smem[38400];  // 150 px * 256B
  const int tid = threadIdx.x;
  const int y   = blockIdx.x >> 1;
  const int x0  = (blockIdx.x & 1) * 48;
  const int lane = tid & 63, w = tid >> 6;
  const int l16 = lane & 15, hi = lane >> 4;

  for (int id = tid; id < 2400; id += 256) {     // 150 px x 16 chunks of 16B
    int px = id >> 4, ch = id & 15;
    int hy = px / 50, hx = px - hy * 50;
    int gy = y + hy - 1, gx = x0 + hx - 1;
    bf16x8 v;
    if (gy >= 0 && gy < 96 && gx >= 0 && gx < 96) {
      const float* src = &att[(gy * 96 + gx) * 128 + ch * 8];
      f32x4 aa = *(const f32x4*)src;
      f32x4 bb = *(const f32x4*)(src + 4);
#pragma unroll
      for (int e = 0; e < 4; ++e) { v[e] = (__bf16)aa[e]; v[4 + e] = (__bf16)bb[e]; }
    } else {
#pragma unroll
      for (int e = 0; e < 8; ++e) v[e] = (__bf16)0.f;
    }
    *(bf16x8*)&smem[px * 256 + ((ch * 16) ^ ((px & 7) << 4))] = v;
  }
  __syncthreads();

  f32x4 acc[2][3];
#pragma unroll
  for (int ot = 0; ot < 2; ++ot) {
    int obase = w * 32 + ot * 16 + hi * 4;
#pragma unroll
    for (int pt = 0; pt < 3; ++pt)
#pragma unroll
      for (int r = 0; r < 4; ++r) acc[ot][pt][r] = bc[obase + r];
  }

  for (int tap = 0; tap < 9; ++tap) {
    int dy = tap / 3, dx = tap - dy * 3;
#pragma unroll
    for (int cc = 0; cc < 4; ++cc) {
      bf16x8 af[2];
#pragma unroll
      for (int ot = 0; ot < 2; ++ot)
        af[ot] = *(const bf16x8*)&wck[(tap * 128 + w * 32 + ot * 16 + l16) * 128 +
                                      cc * 32 + hi * 8];
#pragma unroll
      for (int pt = 0; pt < 3; ++pt) {
        int px = dy * 50 + pt * 16 + l16 + dx;
        bf16x8 bf = *(const bf16x8*)&smem[px * 256 +
                        ((cc * 64 + hi * 16) ^ ((px & 7) << 4))];
#pragma unroll
        for (int ot = 0; ot < 2; ++ot)
          acc[ot][pt] = __builtin_amdgcn_mfma_f32_16x16x32_bf16(af[ot], bf, acc[ot][pt], 0, 0, 0);
      }
    }
  }

#pragma unroll
  for (int ot = 0; ot < 2; ++ot)
#pragma unroll
    for (int pt = 0; pt < 3; ++pt)
#pragma unroll
      for (int r = 0; r < 4; ++r) {
        int o  = w * 32 + ot * 16 + hi * 4 + r;
        int px = y * 96 + x0 + pt * 16 + l16;
        float v = acc[ot][pt][r];
        float ge = 0.5f * v * (1.f + erff(v * 0.70710678118654752f));
        if (resid) ge += resid[o * HWPX + px];
        out[o * HWPX + px] = ge;
      }
}

// ---------------------------------------------------------------------------
extern "C" void kernel_launch(void* const* d_in, const int* in_sizes, int n_in,
                              void* d_out, int out_size, void* d_ws, size_t ws_size,
                              hipStream_t stream) {
  const float* x  = (const float*)d_in[0];
  const float* w1 = (const float*)d_in[1];
  const float* b1 = (const float*)d_in[2];
  const float* a1 = (const float*)d_in[3];
  const float* w2 = (const float*)d_in[4];
  const float* b2 = (const float*)d_in[5];
  const float* a2 = (const float*)d_in[6];
  const float* w3 = (const float*)d_in[7];
  const float* b3 = (const float*)d_in[8];
  const float* a3 = (const float*)d_in[9];
  const float* wc = (const float*)d_in[10];
  const float* bc = (const float*)d_in[11];
  float* out = (float*)d_out;

  char* ws = (char*)d_ws;
  float*  res_a = (float*)(ws + 0);          // 4718592 B
  float*  res_b = (float*)(ws + 4718592);    // 4718592 B
  float*  att   = (float*)(ws + 9437184);    // 4718592 B
  __bf16* Qb    = (__bf16*)(ws + 14155776);  // 2359296 B
  __bf16* Kb    = (__bf16*)(ws + 16515072);  // 2359296 B
  __bf16* Vt    = (__bf16*)(ws + 18874368);  // 2359296 B
  float*  wt    = (float*)(ws + 21233664);   // 196608 B
  __bf16* wck   = (__bf16*)(ws + 21430272);  // 294912 B
  const size_t base_end = 21725184;

  // split-K scratch: Opart (KSPLIT*4718592) + m,l (KSPLIT*36864 each)
  int ksplit = 1;
  if (ws_size >= base_end + 8ull * (4718592 + 2 * 36864)) ksplit = 8;
  else if (ws_size >= base_end + 4ull * (4718592 + 2 * 36864)) ksplit = 4;
  float* Opart = (float*)(ws + base_end);
  float* mArr  = (float*)(ws + base_end + (size_t)ksplit * 4718592);
  float* lArr  = (float*)(ws + base_end + (size_t)ksplit * (4718592 + 36864));

  prep_kernel<<<576, 256, 0, stream>>>(w1, w2, w3, wc, wt, wck);

  const float* in = x;
  for (int u = 0; u < 3; ++u) {
    conv1x1_qkv<<<288, 256, 0, stream>>>(in, wt, b1, b2, b3, a1, a2, a3,
                                         Qb, Kb, Vt);
    if (ksplit > 1) {
      flash_attn<<<dim3(144, ksplit), 256, 0, stream>>>(
          Qb, Kb, Vt, att, Opart, mArr, lArr, 144 / ksplit);
      flash_combine<<<1152, 256, 0, stream>>>(Opart, mArr, lArr, att, ksplit);
    } else {
      flash_attn<<<dim3(144, 1), 256, 0, stream>>>(
          Qb, Kb, Vt, att, nullptr, nullptr, nullptr, 144);
    }
    float* o = (u == 0) ? res_a : ((u == 1) ? res_b : out);
    conv3x3_gelu<<<192, 256, 0, stream>>>(att, wck, bc,
                                          (u == 2) ? x : nullptr, o);
    in = o;
  }
}

// Round 3
// 542.225 us; speedup vs baseline: 2.0315x; 1.2140x over previous
//
#include <hip/hip_runtime.h>

#define HWPX 9216   // 96*96
#define NCH  128

typedef float  f32x4  __attribute__((ext_vector_type(4)));
typedef __bf16 bf16x8 __attribute__((ext_vector_type(8)));

#define SWZ16(row) ((((row) & 7) ^ (((row) >> 3) << 1)) << 4)

// ---------------------------------------------------------------------------
// prep: Wb = (j,o,c) bf16 of w1/w2/w3; wck = (tap,o,c) bf16 of wc;
//       Xb0 = x transposed to (px, c) bf16.
// ---------------------------------------------------------------------------
__global__ __launch_bounds__(256) void prep_kernel(
    const float* __restrict__ w1, const float* __restrict__ w2,
    const float* __restrict__ w3, const float* __restrict__ wc,
    const float* __restrict__ x,
    __bf16* __restrict__ Wb, __bf16* __restrict__ wck,
    __bf16* __restrict__ Xb) {
  int tid = blockIdx.x * 256 + threadIdx.x;
  int nt  = gridDim.x * 256;
  for (int idx = tid; idx < 3 * 16384; idx += nt) {
    int j = idx >> 14;
    const float* w = (j == 0) ? w1 : (j == 1 ? w2 : w3);
    Wb[idx] = (__bf16)w[idx & 16383];          // same (o,c) linear order
  }
  for (int idx = tid; idx < 147456; idx += nt) {   // wc is (O, C, 3, 3)
    int k = idx % 9;
    int rest = idx / 9;            // o*128 + c
    int c = rest & 127, o = rest >> 7;
    wck[(k * 128 + o) * 128 + c] = (__bf16)wc[idx];
  }
  for (int idx = tid; idx < 128 * HWPX; idx += nt) {  // x (c, px) -> Xb (px, c)
    int c = idx / HWPX, p = idx - c * HWPX;
    Xb[p * 128 + c] = (__bf16)x[idx];
  }
}

// ---------------------------------------------------------------------------
// conv1x1 x3 + bias + PReLU as one MFMA GEMM: (9216 px) x (384 o) x (128 c).
// Xb: (px,c) bf16.  Wb: (j*128+o, c) bf16.
// Q,K out as (px,o) bf16; V out as (o,px) bf16.
// Block: 256 thr (4 waves), 64 px, wave w covers o = w*96 .. w*96+95.
// ---------------------------------------------------------------------------
__global__ __launch_bounds__(256) void conv1x1_qkv(
    const __bf16* __restrict__ Xb, const __bf16* __restrict__ Wb,
    const float* __restrict__ b1, const float* __restrict__ b2,
    const float* __restrict__ b3, const float* __restrict__ a1,
    const float* __restrict__ a2, const float* __restrict__ a3,
    __bf16* __restrict__ Q, __bf16* __restrict__ K, __bf16* __restrict__ Vt) {
  const int tid = threadIdx.x, lane = tid & 63, w = tid >> 6;
  const int l16 = lane & 15, hi = lane >> 4;
  const int p0 = blockIdx.x * 64;

  bf16x8 af[4][4];
#pragma unroll
  for (int pxt = 0; pxt < 4; ++pxt)
#pragma unroll
    for (int kc = 0; kc < 4; ++kc)
      af[pxt][kc] = *(const bf16x8*)&Xb[(p0 + pxt * 16 + l16) * 128 + kc * 32 + hi * 8];

  const float s1 = a1[0], s2 = a2[0], s3 = a3[0];

#pragma unroll
  for (int ot = 0; ot < 6; ++ot) {
    const int obase = w * 96 + ot * 16;          // multiple of 16
    const int j = obase >> 7;                    // uniform per (w,ot)
    const int oo = (obase & 127) + l16;
    bf16x8 bfg[4];
#pragma unroll
    for (int kc = 0; kc < 4; ++kc)
      bfg[kc] = *(const bf16x8*)&Wb[(obase + l16) * 128 + kc * 32 + hi * 8];
    f32x4 acc[4];
#pragma unroll
    for (int pxt = 0; pxt < 4; ++pxt) acc[pxt] = (f32x4){0.f, 0.f, 0.f, 0.f};
#pragma unroll
    for (int kc = 0; kc < 4; ++kc)
#pragma unroll
      for (int pxt = 0; pxt < 4; ++pxt)
        acc[pxt] = __builtin_amdgcn_mfma_f32_16x16x32_bf16(af[pxt][kc], bfg[kc], acc[pxt], 0, 0, 0);

    const float* bp = (j == 0) ? b1 : (j == 1 ? b2 : b3);
    const float bias = bp[oo];
    const float sl = (j == 0) ? s1 : (j == 1 ? s2 : s3);
#pragma unroll
    for (int pxt = 0; pxt < 4; ++pxt)
#pragma unroll
      for (int r = 0; r < 4; ++r) {
        float v = acc[pxt][r] + bias;
        v = (v >= 0.f) ? v : sl * v;
        int px = p0 + pxt * 16 + hi * 4 + r;
        if (j == 0)      Q[px * 128 + oo] = (__bf16)v;
        else if (j == 1) K[px * 128 + oo] = (__bf16)v;
        else             Vt[oo * HWPX + px] = (__bf16)v;
      }
  }
}

// ---------------------------------------------------------------------------
// Flash attention, split-K, 8 waves (128 q/block), double-buffered K/V tiles
// staged via global_load_lds with pre-swizzled global source (LDS linear).
// LDS: 2 x (K[64][128] 16KB + V[128][64] 16KB) + 8 x P[16][64] bf16 2KB = 80KB.
// grid = (72, ksplit).  Writes unnormalized Opart + per-query m,l.
// ---------------------------------------------------------------------------
__global__ __launch_bounds__(512) void flash_attn(
    const __bf16* __restrict__ Q, const __bf16* __restrict__ Kb,
    const __bf16* __restrict__ Vt, float* __restrict__ Opart,
    float* __restrict__ mOut, float* __restrict__ lOut, int nt) {
  __shared__ __align__(16) unsigned char smem[81920];
  const int tid  = threadIdx.x;
  const int lane = tid & 63;
  const int w    = tid >> 6;      // 0..7
  const int l16  = lane & 15;
  const int hi   = lane >> 4;
  const int qb   = blockIdx.x * 128;
  const int kt0  = blockIdx.y * nt;

  // staging: waves 0-3 stage K tile (segs 0..15), waves 4-7 stage V (16..31)
  const __bf16* gsrc[4];
  unsigned loff[4];
  long gstep;
  if (w < 4) {
    gstep = 8192;                              // 64 rows * 128
#pragma unroll
    for (int j = 0; j < 4; ++j) {
      int seg = w * 4 + j;
      int row = seg * 4 + (lane >> 4);
      int ch  = lane & 15;
      gsrc[j] = Kb + (size_t)(kt0 * 64 + row) * 128 + (ch ^ (row & 7)) * 8;
      loff[j] = seg * 1024;
    }
  } else {
    gstep = 64;
#pragma unroll
    for (int j = 0; j < 4; ++j) {
      int seg = (w - 4) * 4 + j;
      int d  = seg * 8 + (lane >> 3);
      int ch = lane & 7;
      gsrc[j] = Vt + (size_t)d * HWPX + kt0 * 64 + (ch ^ (d & 7)) * 8;
      loff[j] = 16384 + seg * 1024;
    }
  }

#define STAGE(BUF) do {                                                        \
  _Pragma("unroll")                                                            \
  for (int j = 0; j < 4; ++j) {                                                \
    __builtin_amdgcn_global_load_lds(                                          \
        (const __attribute__((address_space(1))) unsigned int*)gsrc[j],        \
        (__attribute__((address_space(3))) unsigned int*)(smem + (BUF) * 32768 \
                                                          + loff[j]),          \
        16, 0, 0);                                                             \
    gsrc[j] += gstep;                                                          \
  } } while (0)

  // Q fragments in registers
  bf16x8 qf[4];
  const int qrow = qb + w * 16 + l16;
#pragma unroll
  for (int dc = 0; dc < 4; ++dc)
    qf[dc] = *(const bf16x8*)&Q[qrow * 128 + dc * 32 + hi * 8];

  f32x4 oacc[8];
#pragma unroll
  for (int dc = 0; dc < 8; ++dc) oacc[dc] = (f32x4){0.f, 0.f, 0.f, 0.f};
  float m[4], l[4];
#pragma unroll
  for (int r = 0; r < 4; ++r) { m[r] = -INFINITY; l[r] = 0.f; }

  const unsigned pbase = 65536 + w * 2048;

  STAGE(0);
  __syncthreads();

  int cur = 0;
  for (int it = 0; it < nt; ++it) {
    if (it + 1 < nt) STAGE(cur ^ 1);

    const unsigned kb0 = cur * 32768;
    // S = Q K^T   (16 queries x 64 keys per wave)
    f32x4 s[4];
#pragma unroll
    for (int g = 0; g < 4; ++g) {
      s[g] = (f32x4){0.f, 0.f, 0.f, 0.f};
      int row = g * 16 + l16;
#pragma unroll
      for (int dc = 0; dc < 4; ++dc) {
        bf16x8 kf = *(const bf16x8*)&smem[kb0 + row * 256 +
                        ((dc * 64 + hi * 16) ^ ((row & 7) << 4))];
        s[g] = __builtin_amdgcn_mfma_f32_16x16x32_bf16(qf[dc], kf, s[g], 0, 0, 0);
      }
    }

    // online softmax
    float mx[4];
#pragma unroll
    for (int r = 0; r < 4; ++r) {
      mx[r] = fmaxf(fmaxf(s[0][r], s[1][r]), fmaxf(s[2][r], s[3][r]));
      mx[r] = fmaxf(mx[r], __shfl_xor(mx[r], 1));
      mx[r] = fmaxf(mx[r], __shfl_xor(mx[r], 2));
      mx[r] = fmaxf(mx[r], __shfl_xor(mx[r], 4));
      mx[r] = fmaxf(mx[r], __shfl_xor(mx[r], 8));
    }
    float alpha[4], rs[4];
#pragma unroll
    for (int r = 0; r < 4; ++r) {
      float mn = fmaxf(m[r], mx[r]);
      alpha[r] = __expf(m[r] - mn);
      m[r] = mn;
      rs[r] = 0.f;
    }
#pragma unroll
    for (int g = 0; g < 4; ++g)
#pragma unroll
      for (int r = 0; r < 4; ++r) {
        float p = __expf(s[g][r] - m[r]);
        s[g][r] = p;
        rs[r] += p;
      }
#pragma unroll
    for (int r = 0; r < 4; ++r) {
      rs[r] += __shfl_xor(rs[r], 1);
      rs[r] += __shfl_xor(rs[r], 2);
      rs[r] += __shfl_xor(rs[r], 4);
      rs[r] += __shfl_xor(rs[r], 8);
      l[r] = l[r] * alpha[r] + rs[r];
    }
#pragma unroll
    for (int dc = 0; dc < 8; ++dc)
#pragma unroll
      for (int r = 0; r < 4; ++r) oacc[dc][r] *= alpha[r];

    // P -> LDS (per-wave, injective swizzle), then PV
#pragma unroll
    for (int g = 0; g < 4; ++g)
#pragma unroll
      for (int r = 0; r < 4; ++r) {
        int row = hi * 4 + r;
        *(__bf16*)&smem[pbase + row * 128 +
                        ((g * 32 + l16 * 2) ^ SWZ16(row))] = (__bf16)s[g][r];
      }
    bf16x8 pa[2];
#pragma unroll
    for (int kc = 0; kc < 2; ++kc)
      pa[kc] = *(const bf16x8*)&smem[pbase + l16 * 128 +
                   ((kc * 64 + hi * 16) ^ SWZ16(l16))];
#pragma unroll
    for (int dc = 0; dc < 8; ++dc) {
#pragma unroll
      for (int kc = 0; kc < 2; ++kc) {
        int row = dc * 16 + l16;
        bf16x8 vf = *(const bf16x8*)&smem[kb0 + 16384 + row * 128 +
                        ((kc * 64 + hi * 16) ^ ((row & 7) << 4))];
        oacc[dc] = __builtin_amdgcn_mfma_f32_16x16x32_bf16(pa[kc], vf, oacc[dc], 0, 0, 0);
      }
    }
    __syncthreads();
    cur ^= 1;
  }
#undef STAGE

  const int sbase = blockIdx.y * HWPX;
#pragma unroll
  for (int dc = 0; dc < 8; ++dc)
#pragma unroll
    for (int r = 0; r < 4; ++r) {
      int q = qb + w * 16 + hi * 4 + r;
      Opart[(size_t)(sbase + q) * 128 + dc * 16 + l16] = oacc[dc][r];
    }
  if (l16 == 0) {
#pragma unroll
    for (int r = 0; r < 4; ++r) {
      int q = qb + w * 16 + hi * 4 + r;
      mOut[sbase + q] = m[r];
      lOut[sbase + q] = l[r];
    }
  }
}

// ---------------------------------------------------------------------------
// combine split-K partials.
// ---------------------------------------------------------------------------
__global__ __launch_bounds__(256) void flash_combine(
    const float* __restrict__ Opart, const float* __restrict__ mArr,
    const float* __restrict__ lArr, float* __restrict__ att, int ksplit) {
  int idx = blockIdx.x * 256 + threadIdx.x;   // q*32 + d4
  int q = idx >> 5, d4 = idx & 31;
  float M = -INFINITY;
  for (int i = 0; i < ksplit; ++i) M = fmaxf(M, mArr[i * HWPX + q]);
  float denom = 0.f;
  f32x4 acc = (f32x4){0.f, 0.f, 0.f, 0.f};
  for (int i = 0; i < ksplit; ++i) {
    float wi = __expf(mArr[i * HWPX + q] - M);
    denom += lArr[i * HWPX + q] * wi;
    f32x4 v = *(const f32x4*)&Opart[((size_t)i * HWPX + q) * 128 + d4 * 4];
#pragma unroll
    for (int e = 0; e < 4; ++e) acc[e] += wi * v[e];
  }
  float inv = 1.f / denom;
  f32x4 r;
#pragma unroll
  for (int e = 0; e < 4; ++e) r[e] = acc[e] * inv;
  *(f32x4*)&att[(size_t)q * 128 + d4 * 4] = r;
}

// ---------------------------------------------------------------------------
// conv3x3 (SAME) + bias + exact GELU.
// If xbo != nullptr: write bf16 (px,c) activation for the next unit (via LDS
// transpose).  Else: write fp32 out with residual add (final unit).
// ---------------------------------------------------------------------------
__global__ __launch_bounds__(256) void conv3x3_gelu(
    const float* __restrict__ att, const __bf16* __restrict__ wck,
    const float* __restrict__ bc, const float* __restrict__ resid,
    float* __restrict__ out, __bf16* __restrict__ xbo) {
  __shared__ __align__(16) unsigned char smem[38400];  // 150 px * 256B
  const int tid = threadIdx.x;
  const int y   = blockIdx.x >> 1;
  const int x0  = (blockIdx.x & 1) * 48;
  const int lane = tid & 63, w = tid >> 6;
  const int l16 = lane & 15, hi = lane >> 4;

  for (int id = tid; id < 2400; id += 256) {     // 150 px x 16 chunks of 16B
    int px = id >> 4, ch = id & 15;
    int hy = px / 50, hx = px - hy * 50;
    int gy = y + hy - 1, gx = x0 + hx - 1;
    bf16x8 v;
    if (gy >= 0 && gy < 96 && gx >= 0 && gx < 96) {
      const float* src = &att[(gy * 96 + gx) * 128 + ch * 8];
      f32x4 aa = *(const f32x4*)src;
      f32x4 bb = *(const f32x4*)(src + 4);
#pragma unroll
      for (int e = 0; e < 4; ++e) { v[e] = (__bf16)aa[e]; v[4 + e] = (__bf16)bb[e]; }
    } else {
#pragma unroll
      for (int e = 0; e < 8; ++e) v[e] = (__bf16)0.f;
    }
    *(bf16x8*)&smem[px * 256 + ((ch * 16) ^ ((px & 7) << 4))] = v;
  }
  __syncthreads();

  f32x4 acc[2][3];
#pragma unroll
  for (int ot = 0; ot < 2; ++ot) {
    int obase = w * 32 + ot * 16 + hi * 4;
#pragma unroll
    for (int pt = 0; pt < 3; ++pt)
#pragma unroll
      for (int r = 0; r < 4; ++r) acc[ot][pt][r] = bc[obase + r];
  }

  for (int tap = 0; tap < 9; ++tap) {
    int dy = tap / 3, dx = tap - dy * 3;
#pragma unroll
    for (int cc = 0; cc < 4; ++cc) {
      bf16x8 af[2];
#pragma unroll
      for (int ot = 0; ot < 2; ++ot)
        af[ot] = *(const bf16x8*)&wck[(tap * 128 + w * 32 + ot * 16 + l16) * 128 +
                                      cc * 32 + hi * 8];
#pragma unroll
      for (int pt = 0; pt < 3; ++pt) {
        int px = dy * 50 + pt * 16 + l16 + dx;
        bf16x8 bf = *(const bf16x8*)&smem[px * 256 +
                        ((cc * 64 + hi * 16) ^ ((px & 7) << 4))];
#pragma unroll
        for (int ot = 0; ot < 2; ++ot)
          acc[ot][pt] = __builtin_amdgcn_mfma_f32_16x16x32_bf16(af[ot], bf, acc[ot][pt], 0, 0, 0);
      }
    }
  }

  // GELU
  float ge[2][3][4];
#pragma unroll
  for (int ot = 0; ot < 2; ++ot)
#pragma unroll
    for (int pt = 0; pt < 3; ++pt)
#pragma unroll
      for (int r = 0; r < 4; ++r) {
        float v = acc[ot][pt][r];
        ge[ot][pt][r] = 0.5f * v * (1.f + erff(v * 0.70710678118654752f));
      }

  if (xbo) {
    // transpose via LDS to (px, o) bf16, then coalesced store
    __syncthreads();
#pragma unroll
    for (int ot = 0; ot < 2; ++ot)
#pragma unroll
      for (int pt = 0; pt < 3; ++pt)
#pragma unroll
        for (int r = 0; r < 4; ++r) {
          int o  = w * 32 + ot * 16 + hi * 4 + r;
          int pl = pt * 16 + l16;            // 0..47
          *(__bf16*)&smem[pl * 256 + ((o * 2) ^ ((pl & 7) << 4))] =
              (__bf16)ge[ot][pt][r];
        }
    __syncthreads();
    for (int id = tid; id < 768; id += 256) {  // 48 px x 16 chunks
      int pl = id >> 4, ch = id & 15;
      bf16x8 v = *(const bf16x8*)&smem[pl * 256 + ((ch * 16) ^ ((pl & 7) << 4))];
      *(bf16x8*)&xbo[(size_t)(y * 96 + x0 + pl) * 128 + ch * 8] = v;
    }
  } else {
#pragma unroll
    for (int ot = 0; ot < 2; ++ot)
#pragma unroll
      for (int pt = 0; pt < 3; ++pt)
#pragma unroll
        for (int r = 0; r < 4; ++r) {
          int o  = w * 32 + ot * 16 + hi * 4 + r;
          int px = y * 96 + x0 + pt * 16 + l16;
          out[o * HWPX + px] = ge[ot][pt][r] + resid[o * HWPX + px];
        }
  }
}

// ---------------------------------------------------------------------------
extern "C" void kernel_launch(void* const* d_in, const int* in_sizes, int n_in,
                              void* d_out, int out_size, void* d_ws, size_t ws_size,
                              hipStream_t stream) {
  const float* x  = (const float*)d_in[0];
  const float* w1 = (const float*)d_in[1];
  const float* b1 = (const float*)d_in[2];
  const float* a1 = (const float*)d_in[3];
  const float* w2 = (const float*)d_in[4];
  const float* b2 = (const float*)d_in[5];
  const float* a2 = (const float*)d_in[6];
  const float* w3 = (const float*)d_in[7];
  const float* b3 = (const float*)d_in[8];
  const float* a3 = (const float*)d_in[9];
  const float* wc = (const float*)d_in[10];
  const float* bc = (const float*)d_in[11];
  float* out = (float*)d_out;

  char* ws = (char*)d_ws;
  float*  att = (float*)(ws + 0);            // 4718592
  __bf16* Qb  = (__bf16*)(ws + 4718592);     // 2359296
  __bf16* Kb  = (__bf16*)(ws + 7077888);     // 2359296
  __bf16* Vt  = (__bf16*)(ws + 9437184);     // 2359296
  __bf16* Xb  = (__bf16*)(ws + 11796480);    // 2359296
  __bf16* Wb  = (__bf16*)(ws + 14155776);    // 98304
  __bf16* wck = (__bf16*)(ws + 14254080);    // 294912
  const size_t base_end = 14548992;

  int ksplit = 1;
  if (ws_size >= base_end + 8ull * (4718592 + 2 * 36864)) ksplit = 8;
  else if (ws_size >= base_end + 4ull * (4718592 + 2 * 36864)) ksplit = 4;
  else if (ws_size >= base_end + 2ull * (4718592 + 2 * 36864)) ksplit = 2;
  float* Opart = (float*)(ws + base_end);
  float* mArr  = (float*)(ws + base_end + (size_t)ksplit * 4718592);
  float* lArr  = (float*)(ws + base_end + (size_t)ksplit * (4718592 + 36864));

  prep_kernel<<<576, 256, 0, stream>>>(w1, w2, w3, wc, x, Wb, wck, Xb);

  for (int u = 0; u < 3; ++u) {
    conv1x1_qkv<<<144, 256, 0, stream>>>(Xb, Wb, b1, b2, b3, a1, a2, a3,
                                         Qb, Kb, Vt);
    flash_attn<<<dim3(72, ksplit), 512, 0, stream>>>(
        Qb, Kb, Vt, Opart, mArr, lArr, 144 / ksplit);
    flash_combine<<<1152, 256, 0, stream>>>(Opart, mArr, lArr, att, ksplit);
    conv3x3_gelu<<<192, 256, 0, stream>>>(att, wck, bc,
                                          (u == 2) ? x : nullptr,
                                          (u == 2) ? out : nullptr,
                                          (u < 2) ? Xb : nullptr);
  }
}

// Round 5
// 475.986 us; speedup vs baseline: 2.3142x; 1.1392x over previous
//
#include <hip/hip_runtime.h>

#define HWPX 9216   // 96*96
#define NCH  128

typedef float  f32x4  __attribute__((ext_vector_type(4)));
typedef __bf16 bf16x8 __attribute__((ext_vector_type(8)));

#define SWZ16(row) ((((row) & 7) ^ (((row) >> 3) << 1)) << 4)

// DPP reduction over a 16-lane row: xor1, xor2 (quad_perm), then ror4, ror8.
#define DPP_RED(v, OP)                                                         \
  do {                                                                         \
    v = OP(v, __int_as_float(__builtin_amdgcn_update_dpp(                      \
               0, __float_as_int(v), 0xB1, 0xF, 0xF, true)));                  \
    v = OP(v, __int_as_float(__builtin_amdgcn_update_dpp(                      \
               0, __float_as_int(v), 0x4E, 0xF, 0xF, true)));                  \
    v = OP(v, __int_as_float(__builtin_amdgcn_update_dpp(                      \
               0, __float_as_int(v), 0x124, 0xF, 0xF, true)));                 \
    v = OP(v, __int_as_float(__builtin_amdgcn_update_dpp(                      \
               0, __float_as_int(v), 0x128, 0xF, 0xF, true)));                 \
  } while (0)
__device__ __forceinline__ float op_max(float a, float b) { return fmaxf(a, b); }
__device__ __forceinline__ float op_add(float a, float b) { return a + b; }

// ---------------------------------------------------------------------------
// prep: Wb = (j,o,c) bf16 of w1/w2/w3; wck = (tap,o,c) bf16 of wc;
//       Xb = x transposed to (px, c) bf16.
// ---------------------------------------------------------------------------
__global__ __launch_bounds__(256) void prep_kernel(
    const float* __restrict__ w1, const float* __restrict__ w2,
    const float* __restrict__ w3, const float* __restrict__ wc,
    const float* __restrict__ x,
    __bf16* __restrict__ Wb, __bf16* __restrict__ wck,
    __bf16* __restrict__ Xb) {
  int tid = blockIdx.x * 256 + threadIdx.x;
  int nt  = gridDim.x * 256;
  for (int idx = tid; idx < 3 * 16384; idx += nt) {
    int j = idx >> 14;
    const float* w = (j == 0) ? w1 : (j == 1 ? w2 : w3);
    Wb[idx] = (__bf16)w[idx & 16383];
  }
  for (int idx = tid; idx < 147456; idx += nt) {   // wc is (O, C, 3, 3)
    int k = idx % 9;
    int rest = idx / 9;            // o*128 + c
    int c = rest & 127, o = rest >> 7;
    wck[(k * 128 + o) * 128 + c] = (__bf16)wc[idx];
  }
  for (int idx = tid; idx < 128 * HWPX; idx += nt) {  // x (c, px) -> Xb (px, c)
    int c = idx / HWPX, p = idx - c * HWPX;
    Xb[p * 128 + c] = (__bf16)x[idx];
  }
}

// ---------------------------------------------------------------------------
// conv1x1 x3 + bias + PReLU as MFMA GEMM.  grid (144, 6): x = px-tile (64 px),
// y = o-subtile.  Wave w covers obase = w*96 + z*16.
// ---------------------------------------------------------------------------
__global__ __launch_bounds__(256) void conv1x1_qkv(
    const __bf16* __restrict__ Xb, const __bf16* __restrict__ Wb,
    const float* __restrict__ b1, const float* __restrict__ b2,
    const float* __restrict__ b3, const float* __restrict__ a1,
    const float* __restrict__ a2, const float* __restrict__ a3,
    __bf16* __restrict__ Q, __bf16* __restrict__ K, __bf16* __restrict__ Vt) {
  const int tid = threadIdx.x, lane = tid & 63, w = tid >> 6;
  const int l16 = lane & 15, hi = lane >> 4;
  const int p0 = blockIdx.x * 64;
  const int z  = blockIdx.y;

  bf16x8 af[4][4];
#pragma unroll
  for (int pxt = 0; pxt < 4; ++pxt)
#pragma unroll
    for (int kc = 0; kc < 4; ++kc)
      af[pxt][kc] = *(const bf16x8*)&Xb[(p0 + pxt * 16 + l16) * 128 + kc * 32 + hi * 8];

  const int obase = w * 96 + z * 16;
  const int j = obase >> 7;
  const int oo = (obase & 127) + l16;
  bf16x8 bfg[4];
#pragma unroll
  for (int kc = 0; kc < 4; ++kc)
    bfg[kc] = *(const bf16x8*)&Wb[(obase + l16) * 128 + kc * 32 + hi * 8];
  f32x4 acc[4];
#pragma unroll
  for (int pxt = 0; pxt < 4; ++pxt) acc[pxt] = (f32x4){0.f, 0.f, 0.f, 0.f};
#pragma unroll
  for (int kc = 0; kc < 4; ++kc)
#pragma unroll
    for (int pxt = 0; pxt < 4; ++pxt)
      acc[pxt] = __builtin_amdgcn_mfma_f32_16x16x32_bf16(af[pxt][kc], bfg[kc], acc[pxt], 0, 0, 0);

  const float* bp = (j == 0) ? b1 : (j == 1 ? b2 : b3);
  const float bias = bp[oo];
  const float* ap = (j == 0) ? a1 : (j == 1 ? a2 : a3);
  const float sl = ap[0];
#pragma unroll
  for (int pxt = 0; pxt < 4; ++pxt)
#pragma unroll
    for (int r = 0; r < 4; ++r) {
      float v = acc[pxt][r] + bias;
      v = (v >= 0.f) ? v : sl * v;
      int px = p0 + pxt * 16 + hi * 4 + r;
      if (j == 0)      Q[px * 128 + oo] = (__bf16)v;
      else if (j == 1) K[px * 128 + oo] = (__bf16)v;
      else             Vt[oo * HWPX + px] = (__bf16)v;
    }
}

// ---------------------------------------------------------------------------
// Flash attention, split-K, 8 waves (128 q/block), double-buffered K/V via
// global_load_lds (pre-swizzled global source, LDS linear).
// XCD-aware remap: split = flat_block % ksplit so each XCD's L2 caches one
// K/V slice.  DPP softmax (no LDS shuffles) + defer-rescale (THR=8).
// ---------------------------------------------------------------------------
__global__ __launch_bounds__(512) void flash_attn(
    const __bf16* __restrict__ Q, const __bf16* __restrict__ Kb,
    const __bf16* __restrict__ Vt, float* __restrict__ Opart,
    float* __restrict__ mOut, float* __restrict__ lOut, int nt) {
  __shared__ __align__(16) unsigned char smem[81920];
  const int tid  = threadIdx.x;
  const int lane = tid & 63;
  const int w    = tid >> 6;      // 0..7
  const int l16  = lane & 15;
  const int hi   = lane >> 4;
  const int ord  = blockIdx.y * 72 + blockIdx.x;
  const int nsp  = gridDim.y;
  const int split = ord % nsp;
  const int qb   = (ord / nsp) * 128;
  const int kt0  = split * nt;

  // staging: waves 0-3 stage K tile (segs 0..15), waves 4-7 stage V (16..31)
  const __bf16* gsrc[4];
  unsigned loff[4];
  long gstep;
  if (w < 4) {
    gstep = 8192;                              // 64 rows * 128
#pragma unroll
    for (int j = 0; j < 4; ++j) {
      int seg = w * 4 + j;
      int row = seg * 4 + (lane >> 4);
      int ch  = lane & 15;
      gsrc[j] = Kb + (size_t)(kt0 * 64 + row) * 128 + (ch ^ (row & 7)) * 8;
      loff[j] = seg * 1024;
    }
  } else {
    gstep = 64;
#pragma unroll
    for (int j = 0; j < 4; ++j) {
      int seg = (w - 4) * 4 + j;
      int d  = seg * 8 + (lane >> 3);
      int ch = lane & 7;
      gsrc[j] = Vt + (size_t)d * HWPX + kt0 * 64 + (ch ^ (d & 7)) * 8;
      loff[j] = 16384 + seg * 1024;
    }
  }

#define STAGE(BUF) do {                                                        \
  _Pragma("unroll")                                                            \
  for (int j = 0; j < 4; ++j) {                                                \
    __builtin_amdgcn_global_load_lds(                                          \
        (const __attribute__((address_space(1))) unsigned int*)gsrc[j],        \
        (__attribute__((address_space(3))) unsigned int*)(smem + (BUF) * 32768 \
                                                          + loff[j]),          \
        16, 0, 0);                                                             \
    gsrc[j] += gstep;                                                          \
  } } while (0)

  bf16x8 qf[4];
  const int qrow = qb + w * 16 + l16;
#pragma unroll
  for (int dc = 0; dc < 4; ++dc)
    qf[dc] = *(const bf16x8*)&Q[qrow * 128 + dc * 32 + hi * 8];

  f32x4 oacc[8];
#pragma unroll
  for (int dc = 0; dc < 8; ++dc) oacc[dc] = (f32x4){0.f, 0.f, 0.f, 0.f};
  float m[4], l[4];
#pragma unroll
  for (int r = 0; r < 4; ++r) { m[r] = -INFINITY; l[r] = 0.f; }

  const unsigned pbase = 65536 + w * 2048;

  STAGE(0);
  __syncthreads();

  int cur = 0;
  for (int it = 0; it < nt; ++it) {
    if (it + 1 < nt) STAGE(cur ^ 1);

    const unsigned kb0 = cur * 32768;
    // S = Q K^T   (16 queries x 64 keys per wave)
    f32x4 s[4];
    __builtin_amdgcn_s_setprio(1);
#pragma unroll
    for (int g = 0; g < 4; ++g) {
      s[g] = (f32x4){0.f, 0.f, 0.f, 0.f};
      int row = g * 16 + l16;
#pragma unroll
      for (int dc = 0; dc < 4; ++dc) {
        bf16x8 kf = *(const bf16x8*)&smem[kb0 + row * 256 +
                        ((dc * 64 + hi * 16) ^ ((row & 7) << 4))];
        s[g] = __builtin_amdgcn_mfma_f32_16x16x32_bf16(qf[dc], kf, s[g], 0, 0, 0);
      }
    }
    __builtin_amdgcn_s_setprio(0);

    // online softmax: DPP reductions over the 16-lane row (no LDS traffic)
    float mx[4];
#pragma unroll
    for (int r = 0; r < 4; ++r) {
      mx[r] = fmaxf(fmaxf(s[0][r], s[1][r]), fmaxf(s[2][r], s[3][r]));
      DPP_RED(mx[r], op_max);
    }
    // defer-rescale: only pay alpha pass when max grew by > 8
    bool need = false;
#pragma unroll
    for (int r = 0; r < 4; ++r) need = need || (mx[r] > m[r] + 8.f);
    if (__any(need)) {
#pragma unroll
      for (int r = 0; r < 4; ++r) {
        float mn = fmaxf(m[r], mx[r]);
        float alpha = __expf(m[r] - mn);
        m[r] = mn;
        l[r] *= alpha;
#pragma unroll
        for (int dc = 0; dc < 8; ++dc) oacc[dc][r] *= alpha;
      }
    }
    float rs[4];
#pragma unroll
    for (int r = 0; r < 4; ++r) rs[r] = 0.f;
#pragma unroll
    for (int g = 0; g < 4; ++g)
#pragma unroll
      for (int r = 0; r < 4; ++r) {
        float p = __expf(s[g][r] - m[r]);
        s[g][r] = p;
        rs[r] += p;
      }
#pragma unroll
    for (int r = 0; r < 4; ++r) {
      DPP_RED(rs[r], op_add);
      l[r] += rs[r];
    }

    // P -> LDS (per-wave, injective swizzle), then PV
#pragma unroll
    for (int g = 0; g < 4; ++g)
#pragma unroll
      for (int r = 0; r < 4; ++r) {
        int row = hi * 4 + r;
        *(__bf16*)&smem[pbase + row * 128 +
                        ((g * 32 + l16 * 2) ^ SWZ16(row))] = (__bf16)s[g][r];
      }
    bf16x8 pa[2];
#pragma unroll
    for (int kc = 0; kc < 2; ++kc)
      pa[kc] = *(const bf16x8*)&smem[pbase + l16 * 128 +
                   ((kc * 64 + hi * 16) ^ SWZ16(l16))];
    __builtin_amdgcn_s_setprio(1);
#pragma unroll
    for (int dc = 0; dc < 8; ++dc) {
#pragma unroll
      for (int kc = 0; kc < 2; ++kc) {
        int row = dc * 16 + l16;
        bf16x8 vf = *(const bf16x8*)&smem[kb0 + 16384 + row * 128 +
                        ((kc * 64 + hi * 16) ^ ((row & 7) << 4))];
        oacc[dc] = __builtin_amdgcn_mfma_f32_16x16x32_bf16(pa[kc], vf, oacc[dc], 0, 0, 0);
      }
    }
    __builtin_amdgcn_s_setprio(0);
    __syncthreads();
    cur ^= 1;
  }
#undef STAGE

  const int sbase = split * HWPX;
#pragma unroll
  for (int dc = 0; dc < 8; ++dc)
#pragma unroll
    for (int r = 0; r < 4; ++r) {
      int q = qb + w * 16 + hi * 4 + r;
      Opart[(size_t)(sbase + q) * 128 + dc * 16 + l16] = oacc[dc][r];
    }
  if (l16 == 0) {
#pragma unroll
    for (int r = 0; r < 4; ++r) {
      int q = qb + w * 16 + hi * 4 + r;
      mOut[sbase + q] = m[r];
      lOut[sbase + q] = l[r];
    }
  }
}

// ---------------------------------------------------------------------------
// combine split-K partials.
// ---------------------------------------------------------------------------
__global__ __launch_bounds__(256) void flash_combine(
    const float* __restrict__ Opart, const float* __restrict__ mArr,
    const float* __restrict__ lArr, float* __restrict__ att, int ksplit) {
  int idx = blockIdx.x * 256 + threadIdx.x;   // q*32 + d4
  int q = idx >> 5, d4 = idx & 31;
  float M = -INFINITY;
  for (int i = 0; i < ksplit; ++i) M = fmaxf(M, mArr[i * HWPX + q]);
  float denom = 0.f;
  f32x4 acc = (f32x4){0.f, 0.f, 0.f, 0.f};
  for (int i = 0; i < ksplit; ++i) {
    float wi = __expf(mArr[i * HWPX + q] - M);
    denom += lArr[i * HWPX + q] * wi;
    f32x4 v = *(const f32x4*)&Opart[((size_t)i * HWPX + q) * 128 + d4 * 4];
#pragma unroll
    for (int e = 0; e < 4; ++e) acc[e] += wi * v[e];
  }
  float inv = 1.f / denom;
  f32x4 r;
#pragma unroll
  for (int e = 0; e < 4; ++e) r[e] = acc[e] * inv;
  *(f32x4*)&att[(size_t)q * 128 + d4 * 4] = r;
}

// ---------------------------------------------------------------------------
// conv3x3 (SAME) + bias + exact GELU.  32-px tiles, grid 96*3 = 288.
// If xbo != nullptr: write bf16 (px,c) for the next unit (LDS transpose).
// Else: write fp32 out with residual add (final unit).
// ---------------------------------------------------------------------------
__global__ __launch_bounds__(256) void conv3x3_gelu(
    const float* __restrict__ att, const __bf16* __restrict__ wck,
    const float* __restrict__ bc, const float* __restrict__ resid,
    float* __restrict__ out, __bf16* __restrict__ xbo) {
  __shared__ __align__(16) unsigned char smem[26112];  // 102 px * 256B
  const int tid = threadIdx.x;
  const int y   = blockIdx.x / 3;
  const int x0  = (blockIdx.x % 3) * 32;
  const int lane = tid & 63, w = tid >> 6;
  const int l16 = lane & 15, hi = lane >> 4;

  for (int id = tid; id < 1632; id += 256) {     // 102 px x 16 chunks of 16B
    int px = id >> 4, ch = id & 15;
    int hy = px / 34, hx = px - hy * 34;
    int gy = y + hy - 1, gx = x0 + hx - 1;
    bf16x8 v;
    if (gy >= 0 && gy < 96 && gx >= 0 && gx < 96) {
      const float* src = &att[(gy * 96 + gx) * 128 + ch * 8];
      f32x4 aa = *(const f32x4*)src;
      f32x4 bb = *(const f32x4*)(src + 4);
#pragma unroll
      for (int e = 0; e < 4; ++e) { v[e] = (__bf16)aa[e]; v[4 + e] = (__bf16)bb[e]; }
    } else {
#pragma unroll
      for (int e = 0; e < 8; ++e) v[e] = (__bf16)0.f;
    }
    *(bf16x8*)&smem[px * 256 + ((ch * 16) ^ ((px & 7) << 4))] = v;
  }
  __syncthreads();

  f32x4 acc[2][2];
#pragma unroll
  for (int ot = 0; ot < 2; ++ot) {
    int obase = w * 32 + ot * 16 + hi * 4;
#pragma unroll
    for (int pt = 0; pt < 2; ++pt)
#pragma unroll
      for (int r = 0; r < 4; ++r) acc[ot][pt][r] = bc[obase + r];
  }

  for (int tap = 0; tap < 9; ++tap) {
    int dy = tap / 3, dx = tap - dy * 3;
#pragma unroll
    for (int cc = 0; cc < 4; ++cc) {
      bf16x8 af[2];
#pragma unroll
      for (int ot = 0; ot < 2; ++ot)
        af[ot] = *(const bf16x8*)&wck[(tap * 128 + w * 32 + ot * 16 + l16) * 128 +
                                      cc * 32 + hi * 8];
#pragma unroll
      for (int pt = 0; pt < 2; ++pt) {
        int px = dy * 34 + pt * 16 + l16 + dx;
        bf16x8 bf = *(const bf16x8*)&smem[px * 256 +
                        ((cc * 64 + hi * 16) ^ ((px & 7) << 4))];
#pragma unroll
        for (int ot = 0; ot < 2; ++ot)
          acc[ot][pt] = __builtin_amdgcn_mfma_f32_16x16x32_bf16(af[ot], bf, acc[ot][pt], 0, 0, 0);
      }
    }
  }

  // GELU
  float ge[2][2][4];
#pragma unroll
  for (int ot = 0; ot < 2; ++ot)
#pragma unroll
    for (int pt = 0; pt < 2; ++pt)
#pragma unroll
      for (int r = 0; r < 4; ++r) {
        float v = acc[ot][pt][r];
        ge[ot][pt][r] = 0.5f * v * (1.f + erff(v * 0.70710678118654752f));
      }

  if (xbo) {
    __syncthreads();
#pragma unroll
    for (int ot = 0; ot < 2; ++ot)
#pragma unroll
      for (int pt = 0; pt < 2; ++pt)
#pragma unroll
        for (int r = 0; r < 4; ++r) {
          int o  = w * 32 + ot * 16 + hi * 4 + r;
          int pl = pt * 16 + l16;            // 0..31
          *(__bf16*)&smem[pl * 256 + ((o * 2) ^ ((pl & 7) << 4))] =
              (__bf16)ge[ot][pt][r];
        }
    __syncthreads();
    for (int id = tid; id < 512; id += 256) {  // 32 px x 16 chunks
      int pl = id >> 4, ch = id & 15;
      bf16x8 v = *(const bf16x8*)&smem[pl * 256 + ((ch * 16) ^ ((pl & 7) << 4))];
      *(bf16x8*)&xbo[(size_t)(y * 96 + x0 + pl) * 128 + ch * 8] = v;
    }
  } else {
#pragma unroll
    for (int ot = 0; ot < 2; ++ot)
#pragma unroll
      for (int pt = 0; pt < 2; ++pt)
#pragma unroll
        for (int r = 0; r < 4; ++r) {
          int o  = w * 32 + ot * 16 + hi * 4 + r;
          int px = y * 96 + x0 + pt * 16 + l16;
          out[o * HWPX + px] = ge[ot][pt][r] + resid[o * HWPX + px];
        }
  }
}

// ---------------------------------------------------------------------------
extern "C" void kernel_launch(void* const* d_in, const int* in_sizes, int n_in,
                              void* d_out, int out_size, void* d_ws, size_t ws_size,
                              hipStream_t stream) {
  const float* x  = (const float*)d_in[0];
  const float* w1 = (const float*)d_in[1];
  const float* b1 = (const float*)d_in[2];
  const float* a1 = (const float*)d_in[3];
  const float* w2 = (const float*)d_in[4];
  const float* b2 = (const float*)d_in[5];
  const float* a2 = (const float*)d_in[6];
  const float* w3 = (const float*)d_in[7];
  const float* b3 = (const float*)d_in[8];
  const float* a3 = (const float*)d_in[9];
  const float* wc = (const float*)d_in[10];
  const float* bc = (const float*)d_in[11];
  float* out = (float*)d_out;

  char* ws = (char*)d_ws;
  float*  att = (float*)(ws + 0);            // 4718592
  __bf16* Qb  = (__bf16*)(ws + 4718592);     // 2359296
  __bf16* Kb  = (__bf16*)(ws + 7077888);     // 2359296
  __bf16* Vt  = (__bf16*)(ws + 9437184);     // 2359296
  __bf16* Xb  = (__bf16*)(ws + 11796480);    // 2359296
  __bf16* Wb  = (__bf16*)(ws + 14155776);    // 98304
  __bf16* wck = (__bf16*)(ws + 14254080);    // 294912
  const size_t base_end = 14548992;

  int ksplit = 1;
  if (ws_size >= base_end + 8ull * (4718592 + 2 * 36864)) ksplit = 8;
  else if (ws_size >= base_end + 4ull * (4718592 + 2 * 36864)) ksplit = 4;
  else if (ws_size >= base_end + 2ull * (4718592 + 2 * 36864)) ksplit = 2;
  float* Opart = (float*)(ws + base_end);
  float* mArr  = (float*)(ws + base_end + (size_t)ksplit * 4718592);
  float* lArr  = (float*)(ws + base_end + (size_t)ksplit * (4718592 + 36864));

  prep_kernel<<<576, 256, 0, stream>>>(w1, w2, w3, wc, x, Wb, wck, Xb);

  for (int u = 0; u < 3; ++u) {
    conv1x1_qkv<<<dim3(144, 6), 256, 0, stream>>>(Xb, Wb, b1, b2, b3, a1, a2, a3,
                                                  Qb, Kb, Vt);
    flash_attn<<<dim3(72, ksplit), 512, 0, stream>>>(
        Qb, Kb, Vt, Opart, mArr, lArr, 144 / ksplit);
    flash_combine<<<1152, 256, 0, stream>>>(Opart, mArr, lArr, att, ksplit);
    conv3x3_gelu<<<288, 256, 0, stream>>>(att, wck, bc,
                                          (u == 2) ? x : nullptr,
                                          (u == 2) ? out : nullptr,
                                          (u < 2) ? Xb : nullptr);
  }
}